// Round 11
// baseline (399.193 us; speedup 1.0000x reference)
//
#include <hip/hip_runtime.h>
#include <cstdint>
#include <cstddef>

#define TOKENS 8192
#define IN_F   4096
#define OUT_F  4096
#define QMAXF  127.0f
#define EPSF   1e-8f

typedef int i32x4 __attribute__((ext_vector_type(4)));

__device__ __forceinline__ void gload16(const void* g, void* l) {
    __builtin_amdgcn_global_load_lds(
        (const __attribute__((address_space(1))) void*)g,
        (__attribute__((address_space(3))) void*)l,
        16, 0, 0);
}

__device__ __forceinline__ void bar() {
    asm volatile("" ::: "memory");
    __builtin_amdgcn_s_barrier();
    asm volatile("" ::: "memory");
}

// rule #18: inline-asm lgkmcnt(0) needs a following sched_barrier(0)
__device__ __forceinline__ void lgkm0_fence() {
    asm volatile("s_waitcnt lgkmcnt(0)" ::: "memory");
    __builtin_amdgcn_sched_barrier(0);
}

__device__ __forceinline__ int quant1(float v, float inv) {
    int q = (int)rintf(v * inv);
    q = q > 127 ? 127 : q;
    q = q < -127 ? -127 : q;
    return q;
}

__device__ __forceinline__ unsigned int pack4i(int a, int b, int c, int d) {
    return (unsigned int)(a & 255) | ((unsigned int)(b & 255) << 8) |
           ((unsigned int)(c & 255) << 16) | ((unsigned int)(d & 255) << 24);
}

// One block per token: absmax reduce + int8 quantize.
__global__ __launch_bounds__(256) void quant_x_kernel(const float* __restrict__ x,
                                                      signed char* __restrict__ xq,
                                                      float* __restrict__ xscale) {
    const int t   = blockIdx.x;
    const int tid = threadIdx.x;
    const float* xr = x + (size_t)t * IN_F + tid * 16;

    float4 v[4];
    float am = 0.0f;
#pragma unroll
    for (int i = 0; i < 4; ++i) {
        v[i] = ((const float4*)xr)[i];
        am = fmaxf(am, fmaxf(fmaxf(fabsf(v[i].x), fabsf(v[i].y)),
                             fmaxf(fabsf(v[i].z), fabsf(v[i].w))));
    }
#pragma unroll
    for (int off = 32; off >= 1; off >>= 1)
        am = fmaxf(am, __shfl_xor(am, off));

    __shared__ float wmax[4];
    const int wid = tid >> 6, lane = tid & 63;
    if (lane == 0) wmax[wid] = am;
    __syncthreads();
    am = fmaxf(fmaxf(wmax[0], wmax[1]), fmaxf(wmax[2], wmax[3]));

    const float s   = fmaxf(am, EPSF) / QMAXF;
    const float inv = QMAXF / fmaxf(am, EPSF);
    if (tid == 0) xscale[t] = s;

    unsigned int w[4];
#pragma unroll
    for (int i = 0; i < 4; ++i) {
        w[i] = pack4i(quant1(v[i].x, inv), quant1(v[i].y, inv),
                      quant1(v[i].z, inv), quant1(v[i].w, inv));
    }
    *(uint4*)(xq + (size_t)t * IN_F + tid * 16) = make_uint4(w[0], w[1], w[2], w[3]);
}

// Repack int32-held int8 weights into dense int8.
__global__ __launch_bounds__(256) void pack_w_kernel(const int* __restrict__ w,
                                                     signed char* __restrict__ wq) {
    const size_t idx = (size_t)blockIdx.x * 256 + threadIdx.x;
    const int4* src = (const int4*)w + idx * 4;
    unsigned int o[4];
#pragma unroll
    for (int i = 0; i < 4; ++i) {
        int4 u = src[i];
        o[i] = pack4i(u.x, u.y, u.z, u.w);
    }
    ((uint4*)wq)[idx] = make_uint4(o[0], o[1], o[2], o[3]);
}

// R11: A-operand DIRECT global->register (no LDS), B-only LDS staging.
// 256x256 tile, 8 waves (2Mx4N), wave tile 128x64, mfma_i32_16x16x64_i8.
// Per 64B K-half: issue 8 A-loads (for h+1) + 2 B-gloads (for h+2),
// ds_read 4 B-frags, lgkm fence, 32 MFMA, vmcnt(2) [drains B(h+1)+A(h+1),
// keeps B(h+2) in flight], barrier. A-regs double-buffered (aC/aN swap,
// loop unrolled by 2 halves). B: 4 slots x 16 KB, conflict-free
// transposed-window layout (0 conflicts verified R3-R10).
__global__ __launch_bounds__(512, 2) void gemm_kernel(const signed char* __restrict__ xq,
                                                      const signed char* __restrict__ wq,
                                                      const float* __restrict__ xscale,
                                                      const float* __restrict__ wscale,
                                                      const float* __restrict__ bias,
                                                      float* __restrict__ out) {
    __shared__ __align__(16) char Blds[4 * 16384];   // 64 KB

    const int tid  = threadIdx.x;
    const int lane = tid & 63;
    const int wid  = tid >> 6;
    const int wr   = wid >> 2;   // 0..1
    const int wc   = wid & 3;    // 0..3

    // XCD-aware bijective swizzle (512 blocks, 512 % 8 == 0)
    const int bid = blockIdx.x;
    const int swz = (bid & 7) * 64 + (bid >> 3);
    const int bm0 = (swz >> 4) * 256;   // 32 m-tiles
    const int bn0 = (swz & 15) * 256;   // 16 n-tiles

    // ---- B staging map (2 gload16 calls cover 256 rows x 64 B) ----
    const int srow = ((tid >> 6) << 4) + (tid & 15);   // row within 128-row call
    const int sgrn = ((tid >> 4) & 3) << 4;
    const signed char* pB = wq + (size_t)(bn0 + srow) * IN_F + sgrn;
    const int ldst = tid * 16;

    // ---- A per-lane 32-bit voffsets (8 fragments) ----
    const signed char* pAblk = xq + (size_t)bm0 * IN_F;  // uniform base
    int vA[8];
#pragma unroll
    for (int mi = 0; mi < 8; ++mi)
        vA[mi] = (wr * 128 + mi * 16 + (lane & 15)) * IN_F + (lane >> 4) * 16;

    // ---- B fragment read offsets (slot-relative) ----
    const int lrd = (lane >> 4) * 256 + (lane & 15) * 16;
    int b_off[4];
#pragma unroll
    for (int ni = 0; ni < 4; ++ni) b_off[ni] = (wc * 4 + ni) * 1024 + lrd;

    i32x4 acc[8][4];
#pragma unroll
    for (int mi = 0; mi < 8; ++mi)
#pragma unroll
        for (int ni = 0; ni < 4; ++ni)
#pragma unroll
            for (int r = 0; r < 4; ++r) acc[mi][ni][r] = 0;

    // ---- prologue: B(0)->slot0, B(1)->slot1; A(0)->aC ----
    gload16(pB,                           Blds + ldst);
    gload16(pB + (size_t)128 * IN_F,      Blds + 8192 + ldst);
    gload16(pB + 64,                      Blds + 16384 + ldst);
    gload16(pB + (size_t)128 * IN_F + 64, Blds + 16384 + 8192 + ldst);

    i32x4 aC[8], aN[8], b[4];
#pragma unroll
    for (int mi = 0; mi < 8; ++mi)
        aC[mi] = *(const i32x4*)(pAblk + vA[mi]);

    asm volatile("s_waitcnt vmcnt(0)" ::: "memory");
    bar();

    // ---- main loop: t = 0..30 handles halves h0=2t, h1=2t+1 (h <= 61) ----
    for (int t = 0; t < 31; ++t) {
        const int h0 = 2 * t;

        // ======== half h0: consume aC, B slot h0&3 ========
        {
            const char* S = Blds + (h0 & 3) * 16384;
            const signed char* pAh = pAblk + (h0 + 1) * 64;
#pragma unroll
            for (int mi = 0; mi < 8; ++mi) aN[mi] = *(const i32x4*)(pAh + vA[mi]);
            {   // stage B(h0+2) -> slot (h0+2)&3
                char* D = Blds + ((h0 + 2) & 3) * 16384;
                const int ko = (h0 + 2) * 64;
                gload16(pB + ko,                      D + ldst);
                gload16(pB + (size_t)128 * IN_F + ko, D + 8192 + ldst);
            }
#pragma unroll
            for (int ni = 0; ni < 4; ++ni) b[ni] = *(const i32x4*)(S + b_off[ni]);
            lgkm0_fence();
            __builtin_amdgcn_s_setprio(1);
#pragma unroll
            for (int mi = 0; mi < 8; ++mi)
#pragma unroll
                for (int ni = 0; ni < 4; ++ni)
                    acc[mi][ni] = __builtin_amdgcn_mfma_i32_16x16x64_i8(aC[mi], b[ni], acc[mi][ni], 0, 0, 0);
            __builtin_amdgcn_s_setprio(0);
            asm volatile("s_waitcnt vmcnt(2)" ::: "memory");  // drain B(h0+1)+A(h0+1)
            bar();
        }

        // ======== half h1 = h0+1: consume aN, B slot h1&3 ========
        {
            const int h1 = h0 + 1;
            const char* S = Blds + (h1 & 3) * 16384;
            const signed char* pAh = pAblk + (h1 + 1) * 64;
#pragma unroll
            for (int mi = 0; mi < 8; ++mi) aC[mi] = *(const i32x4*)(pAh + vA[mi]);
            {   // stage B(h1+2)
                char* D = Blds + ((h1 + 2) & 3) * 16384;
                const int ko = (h1 + 2) * 64;
                gload16(pB + ko,                      D + ldst);
                gload16(pB + (size_t)128 * IN_F + ko, D + 8192 + ldst);
            }
#pragma unroll
            for (int ni = 0; ni < 4; ++ni) b[ni] = *(const i32x4*)(S + b_off[ni]);
            lgkm0_fence();
            __builtin_amdgcn_s_setprio(1);
#pragma unroll
            for (int mi = 0; mi < 8; ++mi)
#pragma unroll
                for (int ni = 0; ni < 4; ++ni)
                    acc[mi][ni] = __builtin_amdgcn_mfma_i32_16x16x64_i8(aN[mi], b[ni], acc[mi][ni], 0, 0, 0);
            __builtin_amdgcn_s_setprio(0);
            asm volatile("s_waitcnt vmcnt(2)" ::: "memory");  // drain B(h1+1)+A(h1+1)
            bar();
        }
    }

    // ---- tail: halves 62 (aC) and 63 (aN) ----
    {
        const char* S = Blds + (62 & 3) * 16384;
        const signed char* pAh = pAblk + 63 * 64;
#pragma unroll
        for (int mi = 0; mi < 8; ++mi) aN[mi] = *(const i32x4*)(pAh + vA[mi]);
#pragma unroll
        for (int ni = 0; ni < 4; ++ni) b[ni] = *(const i32x4*)(S + b_off[ni]);
        lgkm0_fence();
        __builtin_amdgcn_s_setprio(1);
#pragma unroll
        for (int mi = 0; mi < 8; ++mi)
#pragma unroll
            for (int ni = 0; ni < 4; ++ni)
                acc[mi][ni] = __builtin_amdgcn_mfma_i32_16x16x64_i8(aC[mi], b[ni], acc[mi][ni], 0, 0, 0);
        __builtin_amdgcn_s_setprio(0);
        asm volatile("s_waitcnt vmcnt(0)" ::: "memory");
        bar();
    }
    {
        const char* S = Blds + (63 & 3) * 16384;
#pragma unroll
        for (int ni = 0; ni < 4; ++ni) b[ni] = *(const i32x4*)(S + b_off[ni]);
        lgkm0_fence();
        __builtin_amdgcn_s_setprio(1);
#pragma unroll
        for (int mi = 0; mi < 8; ++mi)
#pragma unroll
            for (int ni = 0; ni < 4; ++ni)
                acc[mi][ni] = __builtin_amdgcn_mfma_i32_16x16x64_i8(aN[mi], b[ni], acc[mi][ni], 0, 0, 0);
        __builtin_amdgcn_s_setprio(0);
    }

    // ---- epilogue: dequant + bias ----
    // 16x16 C/D layout: col = lane&15, row = (lane>>4)*4 + reg
    const int l15 = lane & 15, lq = lane >> 4;
#pragma unroll
    for (int mi = 0; mi < 8; ++mi) {
        const int rbase = bm0 + wr * 128 + mi * 16 + lq * 4;
        float xsv[4];
#pragma unroll
        for (int j = 0; j < 4; ++j) xsv[j] = xscale[rbase + j];
#pragma unroll
        for (int ni = 0; ni < 4; ++ni) {
            const int col = bn0 + wc * 64 + ni * 16 + l15;
            const float wsc = wscale[col];
            const float bv  = bias[col];
#pragma unroll
            for (int j = 0; j < 4; ++j) {
                out[(size_t)(rbase + j) * OUT_F + col] =
                    (float)acc[mi][ni][j] * xsv[j] * wsc + bv;
            }
        }
    }
}

extern "C" void kernel_launch(void* const* d_in, const int* in_sizes, int n_in,
                              void* d_out, int out_size, void* d_ws, size_t ws_size,
                              hipStream_t stream) {
    const float* x      = (const float*)d_in[0];
    const int*   w      = (const int*)d_in[1];     // int8 weights held as int32
    const float* wscale = (const float*)d_in[2];
    const float* bias   = (const float*)d_in[3];
    float* out = (float*)d_out;

    char* ws = (char*)d_ws;
    signed char* xq  = (signed char*)ws;                                   // 33.5 MB
    signed char* wq8 = (signed char*)(ws + (size_t)TOKENS * IN_F);         // 16.8 MB
    float* xscale    = (float*)(ws + (size_t)TOKENS * IN_F + (size_t)OUT_F * IN_F);

    quant_x_kernel<<<TOKENS, 256, 0, stream>>>(x, xq, xscale);
    pack_w_kernel<<<(OUT_F * (IN_F / 16)) / 256, 256, 0, stream>>>(w, wq8);
    gemm_kernel<<<(TOKENS / 256) * (OUT_F / 256), 512, 0, stream>>>(
        xq, wq8, xscale, wscale, bias, out);
}

// Round 12
// 199.247 us; speedup vs baseline: 2.0035x; 2.0035x over previous
//
#include <hip/hip_runtime.h>
#include <cstdint>
#include <cstddef>

#define TOKENS 8192
#define IN_F   4096
#define OUT_F  4096
#define QMAXF  127.0f
#define EPSF   1e-8f

typedef int i32x4 __attribute__((ext_vector_type(4)));

#define NIT   32                  // iterations; each covers 2 K-halves of 64 B
#define SLOTB 32768               // half-slot: A 16 KB + B 16 KB
#define LDS_TOTAL (4 * SLOTB)     // 131072

__device__ __forceinline__ void gload16(const void* g, void* l) {
    __builtin_amdgcn_global_load_lds(
        (const __attribute__((address_space(1))) void*)g,
        (__attribute__((address_space(3))) void*)l,
        16, 0, 0);
}

__device__ __forceinline__ void bar() {
    asm volatile("" ::: "memory");
    __builtin_amdgcn_s_barrier();
    asm volatile("" ::: "memory");
}

// rule #18: inline-asm lgkmcnt(0) needs a following sched_barrier(0)
__device__ __forceinline__ void lgkm0_fence() {
    asm volatile("s_waitcnt lgkmcnt(0)" ::: "memory");
    __builtin_amdgcn_sched_barrier(0);
}

__device__ __forceinline__ int quant1(float v, float inv) {
    int q = (int)rintf(v * inv);
    q = q > 127 ? 127 : q;
    q = q < -127 ? -127 : q;
    return q;
}

__device__ __forceinline__ unsigned int pack4i(int a, int b, int c, int d) {
    return (unsigned int)(a & 255) | ((unsigned int)(b & 255) << 8) |
           ((unsigned int)(c & 255) << 16) | ((unsigned int)(d & 255) << 24);
}

// One block per token: absmax reduce + int8 quantize.
__global__ __launch_bounds__(256) void quant_x_kernel(const float* __restrict__ x,
                                                      signed char* __restrict__ xq,
                                                      float* __restrict__ xscale) {
    const int t   = blockIdx.x;
    const int tid = threadIdx.x;
    const float* xr = x + (size_t)t * IN_F + tid * 16;

    float4 v[4];
    float am = 0.0f;
#pragma unroll
    for (int i = 0; i < 4; ++i) {
        v[i] = ((const float4*)xr)[i];
        am = fmaxf(am, fmaxf(fmaxf(fabsf(v[i].x), fabsf(v[i].y)),
                             fmaxf(fabsf(v[i].z), fabsf(v[i].w))));
    }
#pragma unroll
    for (int off = 32; off >= 1; off >>= 1)
        am = fmaxf(am, __shfl_xor(am, off));

    __shared__ float wmax[4];
    const int wid = tid >> 6, lane = tid & 63;
    if (lane == 0) wmax[wid] = am;
    __syncthreads();
    am = fmaxf(fmaxf(wmax[0], wmax[1]), fmaxf(wmax[2], wmax[3]));

    const float s   = fmaxf(am, EPSF) / QMAXF;
    const float inv = QMAXF / fmaxf(am, EPSF);
    if (tid == 0) xscale[t] = s;

    unsigned int w[4];
#pragma unroll
    for (int i = 0; i < 4; ++i) {
        w[i] = pack4i(quant1(v[i].x, inv), quant1(v[i].y, inv),
                      quant1(v[i].z, inv), quant1(v[i].w, inv));
    }
    *(uint4*)(xq + (size_t)t * IN_F + tid * 16) = make_uint4(w[0], w[1], w[2], w[3]);
}

// Repack int32-held int8 weights into dense int8.
__global__ __launch_bounds__(256) void pack_w_kernel(const int* __restrict__ w,
                                                     signed char* __restrict__ wq) {
    const size_t idx = (size_t)blockIdx.x * 256 + threadIdx.x;
    const int4* src = (const int4*)w + idx * 4;
    unsigned int o[4];
#pragma unroll
    for (int i = 0; i < 4; ++i) {
        int4 u = src[i];
        o[i] = pack4i(u.x, u.y, u.z, u.w);
    }
    ((uint4*)wq)[idx] = make_uint4(o[0], o[1], o[2], o[3]);
}

// R12 = exact revert to R8 (best measured: 199.67 us total, gemm 162 us).
// i8 port of the m201 8-phase 256^2 template: mfma_i32_16x16x64_i8,
// 8 waves (2Mx4N), per-wave C = 128x64 (8x4 tiles), iteration = 2 K-halves
// (64 B each) = 4 phases. Phase: {ds_read 8-or-4 b128 | 2 gload_lds ->
// barrier -> lgkmcnt(0)+sched_barrier(0) -> setprio(1) -> 16 MFMA ->
// setprio(0) -> [vmcnt(8) at half boundary] -> barrier}.
// 4 half-slots (128 KB), stage lead = 3 halves -> vmcnt(8) never blocks.
// LDS window layout (16 rows x 64 B): addr = win*1024 + (l>>4)*256 +
// (l&15)*16 -> 0 bank conflicts (verified R3-R10).
__global__ __launch_bounds__(512, 2) void gemm_kernel(const signed char* __restrict__ xq,
                                                      const signed char* __restrict__ wq,
                                                      const float* __restrict__ xscale,
                                                      const float* __restrict__ wscale,
                                                      const float* __restrict__ bias,
                                                      float* __restrict__ out) {
    extern __shared__ __align__(16) char lds[];

    const int tid  = threadIdx.x;
    const int wid  = tid >> 6;
    const int lane = tid & 63;
    const int wr   = wid >> 2;   // 0..1
    const int wc   = wid & 3;    // 0..3

    // XCD-aware bijective swizzle (512 blocks, 512 % 8 == 0)
    const int bid = blockIdx.x;
    const int swz = (bid & 7) * 64 + (bid >> 3);
    const int bm0 = (swz >> 4) * 256;   // 32 m-tiles
    const int bn0 = (swz & 15) * 256;   // 16 n-tiles

    // ---- staging map: call c covers rows [c*128, c*128+128) of the panel ----
    const int srow = ((tid >> 6) << 4) + (tid & 15);   // row within 128-row call
    const int sgrn = ((tid >> 4) & 3) << 4;            // 16B k-granule within 64B half
    const signed char* pA = xq + (size_t)(bm0 + srow) * IN_F + sgrn;
    const signed char* pB = wq + (size_t)(bn0 + srow) * IN_F + sgrn;
    const int ldst = tid * 16;

    // ---- fragment read offsets (within slot) ----
    const int lrd = (lane >> 4) * 256 + (lane & 15) * 16;
    int a_off[8], b_off[4];
#pragma unroll
    for (int mi = 0; mi < 8; ++mi) a_off[mi] = (wr * 8 + mi) * 1024 + lrd;
#pragma unroll
    for (int ni = 0; ni < 4; ++ni) b_off[ni] = 16384 + (wc * 4 + ni) * 1024 + lrd;

    i32x4 acc[8][4];
#pragma unroll
    for (int mi = 0; mi < 8; ++mi)
#pragma unroll
        for (int ni = 0; ni < 4; ++ni)
#pragma unroll
            for (int r = 0; r < 4; ++r) acc[mi][ni][r] = 0;

    // ---- prologue: stage halves 0,1,2 -> slots 0,1,2 (order A,B per half) ----
#pragma unroll
    for (int s = 0; s < 3; ++s) {
        char* S = lds + s * SLOTB;
        const int ko = s * 64;
        gload16(pA + ko,                         S + ldst);
        gload16(pA + (size_t)128 * IN_F + ko,    S + 8192 + ldst);
        gload16(pB + ko,                         S + 16384 + ldst);
        gload16(pB + (size_t)128 * IN_F + ko,    S + 24576 + ldst);
    }
    asm volatile("s_waitcnt vmcnt(8)" ::: "memory");  // half 0 landed
    bar();

    for (int t = 0; t < NIT; ++t) {
        const int h0 = 2 * t;
        const char* S0 = lds + (h0 & 3) * SLOTB;
        const char* S1 = lds + ((h0 + 1) & 3) * SLOTB;
        char* G3 = lds + ((h0 + 3) & 3) * SLOTB;   // dest for half h0+3
        char* G4 = lds + ((h0 + 4) & 3) * SLOTB;   // dest for half h0+4
        const bool st0 = (h0 + 3) < 64;
        const bool st1 = (h0 + 4) < 64;
        const int ko0 = (h0 + 3) * 64;
        const int ko1 = (h0 + 4) * 64;

        i32x4 a[4], b[4];

        // ---------- phase 0: half h0, mi 0-3, all ni ----------
#pragma unroll
        for (int ni = 0; ni < 4; ++ni) b[ni] = *(const i32x4*)(S0 + b_off[ni]);
#pragma unroll
        for (int mi = 0; mi < 4; ++mi) a[mi] = *(const i32x4*)(S0 + a_off[mi]);
        if (st0) {
            gload16(pA + ko0,                      G3 + ldst);
            gload16(pA + (size_t)128 * IN_F + ko0, G3 + 8192 + ldst);
        }
        bar();
        lgkm0_fence();
        __builtin_amdgcn_s_setprio(1);
#pragma unroll
        for (int mi = 0; mi < 4; ++mi)
#pragma unroll
            for (int ni = 0; ni < 4; ++ni)
                acc[mi][ni] = __builtin_amdgcn_mfma_i32_16x16x64_i8(a[mi], b[ni], acc[mi][ni], 0, 0, 0);
        __builtin_amdgcn_s_setprio(0);
        bar();

        // ---------- phase 1: half h0, mi 4-7 (B held) ----------
#pragma unroll
        for (int mi = 0; mi < 4; ++mi) a[mi] = *(const i32x4*)(S0 + a_off[4 + mi]);
        if (st0) {
            gload16(pB + ko0,                      G3 + 16384 + ldst);
            gload16(pB + (size_t)128 * IN_F + ko0, G3 + 24576 + ldst);
        }
        bar();
        lgkm0_fence();
        __builtin_amdgcn_s_setprio(1);
#pragma unroll
        for (int mi = 0; mi < 4; ++mi)
#pragma unroll
            for (int ni = 0; ni < 4; ++ni)
                acc[4 + mi][ni] = __builtin_amdgcn_mfma_i32_16x16x64_i8(a[mi], b[ni], acc[4 + mi][ni], 0, 0, 0);
        __builtin_amdgcn_s_setprio(0);
        // half boundary: ensure half h0+1 landed (its loads are 3 halves old)
        if (t < NIT - 1) {
            asm volatile("s_waitcnt vmcnt(8)" ::: "memory");
        } else {
            asm volatile("s_waitcnt vmcnt(0)" ::: "memory");
        }
        bar();

        // ---------- phase 2: half h0+1, mi 0-3, all ni ----------
#pragma unroll
        for (int ni = 0; ni < 4; ++ni) b[ni] = *(const i32x4*)(S1 + b_off[ni]);
#pragma unroll
        for (int mi = 0; mi < 4; ++mi) a[mi] = *(const i32x4*)(S1 + a_off[mi]);
        if (st1) {
            gload16(pA + ko1,                      G4 + ldst);
            gload16(pA + (size_t)128 * IN_F + ko1, G4 + 8192 + ldst);
        }
        bar();
        lgkm0_fence();
        __builtin_amdgcn_s_setprio(1);
#pragma unroll
        for (int mi = 0; mi < 4; ++mi)
#pragma unroll
            for (int ni = 0; ni < 4; ++ni)
                acc[mi][ni] = __builtin_amdgcn_mfma_i32_16x16x64_i8(a[mi], b[ni], acc[mi][ni], 0, 0, 0);
        __builtin_amdgcn_s_setprio(0);
        bar();

        // ---------- phase 3: half h0+1, mi 4-7 (B held) ----------
#pragma unroll
        for (int mi = 0; mi < 4; ++mi) a[mi] = *(const i32x4*)(S1 + a_off[4 + mi]);
        if (st1) {
            gload16(pB + ko1,                      G4 + 16384 + ldst);
            gload16(pB + (size_t)128 * IN_F + ko1, G4 + 24576 + ldst);
        }
        bar();
        lgkm0_fence();
        __builtin_amdgcn_s_setprio(1);
#pragma unroll
        for (int mi = 0; mi < 4; ++mi)
#pragma unroll
            for (int ni = 0; ni < 4; ++ni)
                acc[4 + mi][ni] = __builtin_amdgcn_mfma_i32_16x16x64_i8(a[mi], b[ni], acc[4 + mi][ni], 0, 0, 0);
        __builtin_amdgcn_s_setprio(0);
        // half boundary: ensure half h0+2 landed before next iteration
        if (t < NIT - 2) {
            asm volatile("s_waitcnt vmcnt(8)" ::: "memory");
        } else if (t == NIT - 2) {
            asm volatile("s_waitcnt vmcnt(4)" ::: "memory");
        } else {
            asm volatile("s_waitcnt vmcnt(0)" ::: "memory");
        }
        bar();
    }

    // ---- epilogue: dequant + bias ----
    // 16x16 C/D layout: col = lane&15, row = (lane>>4)*4 + reg
    const int l15 = lane & 15, lq = lane >> 4;
#pragma unroll
    for (int mi = 0; mi < 8; ++mi) {
        const int rbase = bm0 + wr * 128 + mi * 16 + lq * 4;
        float xsv[4];
#pragma unroll
        for (int j = 0; j < 4; ++j) xsv[j] = xscale[rbase + j];
#pragma unroll
        for (int ni = 0; ni < 4; ++ni) {
            const int col = bn0 + wc * 64 + ni * 16 + l15;
            const float wsc = wscale[col];
            const float bv  = bias[col];
#pragma unroll
            for (int j = 0; j < 4; ++j) {
                out[(size_t)(rbase + j) * OUT_F + col] =
                    (float)acc[mi][ni][j] * xsv[j] * wsc + bv;
            }
        }
    }
}

extern "C" void kernel_launch(void* const* d_in, const int* in_sizes, int n_in,
                              void* d_out, int out_size, void* d_ws, size_t ws_size,
                              hipStream_t stream) {
    const float* x      = (const float*)d_in[0];
    const int*   w      = (const int*)d_in[1];     // int8 weights held as int32
    const float* wscale = (const float*)d_in[2];
    const float* bias   = (const float*)d_in[3];
    float* out = (float*)d_out;

    char* ws = (char*)d_ws;
    signed char* xq  = (signed char*)ws;                                   // 33.5 MB
    signed char* wq8 = (signed char*)(ws + (size_t)TOKENS * IN_F);         // 16.8 MB
    float* xscale    = (float*)(ws + (size_t)TOKENS * IN_F + (size_t)OUT_F * IN_F);

    (void)hipFuncSetAttribute((const void*)gemm_kernel,
                              hipFuncAttributeMaxDynamicSharedMemorySize, LDS_TOTAL);

    quant_x_kernel<<<TOKENS, 256, 0, stream>>>(x, xq, xscale);
    pack_w_kernel<<<(OUT_F * (IN_F / 16)) / 256, 256, 0, stream>>>(w, wq8);
    gemm_kernel<<<(TOKENS / 256) * (OUT_F / 256), 512, LDS_TOTAL, stream>>>(
        xq, wq8, xscale, wscale, bias, out);
}